// Round 2
// baseline (192.101 us; speedup 1.0000x reference)
//
#include <hip/hip_runtime.h>
#include <hip/hip_bf16.h>
#include <stdint.h>

#define BATCH   16384
#define NCLASS  1000
#define CPAD    1024
#define FDIM    1024
#define MARGINF 5.0f

typedef __attribute__((ext_vector_type(4))) float f32x4;
typedef __attribute__((ext_vector_type(8))) short bf16x8;

__device__ __forceinline__ void gload16(const void* g, void* l) {
    __builtin_amdgcn_global_load_lds(
        (const __attribute__((address_space(1))) void*)g,
        (__attribute__((address_space(3))) void*)l, 16, 0, 0);
}

__device__ __forceinline__ unsigned short f2bf(float f) {
    __hip_bfloat16 h = __float2bfloat16(f);
    return __builtin_bit_cast(unsigned short, h);
}

// ---- prep: blocks [0,1024): centers fp32->bf16 + c2 (pad rows zero / c2=1e30)
//            blocks [1024,3072): x fp32->bf16 ----
__global__ void prep(const float* __restrict__ x, const float* __restrict__ c,
                     unsigned short* __restrict__ xb, unsigned short* __restrict__ cb,
                     float* __restrict__ c2) {
    const int bid = blockIdx.x;
    const int t   = threadIdx.x;
    if (bid < CPAD) {
        const int k = bid;
        if (k >= NCLASS) {
            ((ushort4*)(cb + (size_t)k * FDIM))[t] = make_ushort4(0, 0, 0, 0);
            if (t == 0) c2[k] = 1e30f;
            return;
        }
        float4 v = ((const float4*)(c + (size_t)k * FDIM))[t];
        ushort4 o;
        o.x = f2bf(v.x); o.y = f2bf(v.y); o.z = f2bf(v.z); o.w = f2bf(v.w);
        ((ushort4*)(cb + (size_t)k * FDIM))[t] = o;
        float ss = v.x * v.x + v.y * v.y + v.z * v.z + v.w * v.w;
        #pragma unroll
        for (int s = 1; s < 64; s <<= 1) ss += __shfl_xor(ss, s, 64);
        __shared__ float sred[4];
        int lane = t & 63, wid = t >> 6;
        if (lane == 0) sred[wid] = ss;
        __syncthreads();
        if (t == 0) c2[k] = sred[0] + sred[1] + sred[2] + sred[3];
    } else {
        // x conversion: 2048 blocks, 8 float4s per thread, coalesced
        const int n4 = BATCH * FDIM / 4;
        int i = (bid - CPAD) * 256 + t;
        const int stride = 2048 * 256;
        #pragma unroll
        for (int it = 0; it < 8; ++it, i += stride) {
            if (i < n4) {
                float4 v = ((const float4*)x)[i];
                ushort4 o;
                o.x = f2bf(v.x); o.y = f2bf(v.y); o.z = f2bf(v.z); o.w = f2bf(v.w);
                ((ushort4*)xb)[i] = o;
            }
        }
    }
}

// ---- fused GEMM + per-row partial min.  1D grid:
//   blocks [0,1024):    main  t[r,c]=0.5*c2[c]-dot(x_r, cen_c), 128x128 tiles (128 x 8)
//   blocks [1024,1088): CC    t[r,c]=0.5*c2[c]-dot(cen_r,cen_c), 128x128 tiles (8 x 8)
// LDS exactly 32768 B -> 5 blocks/CU, all 1088 blocks co-resident.
__launch_bounds__(256, 5)
__global__ void gemm_min(const unsigned short* __restrict__ xb,   // [16384][1024] bf16
                         const unsigned short* __restrict__ cb,   // [1024][1024] bf16
                         const float* __restrict__ c2,
                         const int* __restrict__ labels,
                         float* __restrict__ pmin,                // [16384][8]
                         float* __restrict__ cpmin,               // [1024][8]
                         float* __restrict__ pos)                 // [16384]
{
    constexpr int BM = 128, BK = 64, KTOT = 1024, NCT = 8;
    __shared__ __align__(16) char sA[BM * BK * 2];   // 16 KB
    __shared__ __align__(16) char sB[BM * BK * 2];   // 16 KB  (total = 32768 exactly)

    const int bid  = blockIdx.x;
    const bool cc  = (bid >= 1024);
    const int bx   = cc ? (bid - 1024) & 7 : bid & 127;
    const int by   = cc ? (bid - 1024) >> 3 : bid >> 7;

    const int t    = threadIdx.x;
    const int lane = t & 63;
    const int wave = t >> 6;
    const int wrow = wave >> 1, wcol = wave & 1;
    const int lo4  = lane & 15, hi2 = lane >> 4;

    const int rowBase = bx * BM;
    const int colBase = by * BM;
    const unsigned short* A = cc ? cb : xb;
    float* pout = cc ? cpmin : pmin;

    f32x4 acc[4][4];
    #pragma unroll
    for (int m = 0; m < 4; m++)
        #pragma unroll
        for (int n = 0; n < 4; n++) acc[m][n] = (f32x4){0.f, 0.f, 0.f, 0.f};

    const int g_t = t & 7;           // granule within row
    const int r_t = t >> 3;          // row within 32-row chunk

    for (int kt = 0; kt < KTOT / BK; ++kt) {
        __syncthreads();
        const int k0 = kt * BK;
        #pragma unroll
        for (int cch = 0; cch < 4; ++cch) {
            const int row = cch * 32 + r_t;
            const int sc  = g_t ^ (row & 7);     // inverse-swizzled global granule
            const unsigned short* ga = A  + (size_t)(rowBase + row) * KTOT + k0 + sc * 8;
            const unsigned short* gb = cb + (size_t)(colBase + row) * KTOT + k0 + sc * 8;
            char* la = sA + (cch * 256 + (t & 192)) * 16;   // wave-uniform base; HW adds lane*16
            char* lb = sB + (cch * 256 + (t & 192)) * 16;
            gload16(ga, la);
            gload16(gb, lb);
        }
        __syncthreads();
        #pragma unroll
        for (int ks = 0; ks < 2; ++ks) {
            bf16x8 af[4], bfr[4];
            #pragma unroll
            for (int m = 0; m < 4; m++) {
                const int r    = wrow * 64 + m * 16 + lo4;
                const int slot = (ks * 4 + hi2) ^ (r & 7);
                af[m] = *(const bf16x8*)(sA + r * 128 + slot * 16);
            }
            #pragma unroll
            for (int n = 0; n < 4; n++) {
                const int r    = wcol * 64 + n * 16 + lo4;
                const int slot = (ks * 4 + hi2) ^ (r & 7);
                bfr[n] = *(const bf16x8*)(sB + r * 128 + slot * 16);
            }
            #pragma unroll
            for (int m = 0; m < 4; m++)
                #pragma unroll
                for (int n = 0; n < 4; n++)
                    acc[m][n] = __builtin_amdgcn_mfma_f32_16x16x32_bf16(af[m], bfr[n], acc[m][n], 0, 0, 0);
        }
    }

    // ---- epilogue: bias + exclusion + per-row min ----
    __syncthreads();                    // all LDS reads done; sA reused as sPM
    float* sPM = (float*)sA;            // [2][128]

    float bias[4]; int colg[4];
    #pragma unroll
    for (int n = 0; n < 4; n++) {
        const int col = colBase + wcol * 64 + n * 16 + lo4;
        colg[n] = col;
        bias[n] = 0.5f * c2[col];          // c2[col>=1000]=1e30 masks padding
    }
    #pragma unroll
    for (int m = 0; m < 4; m++) {
        #pragma unroll
        for (int j = 0; j < 4; j++) {
            const int rloc  = wrow * 64 + m * 16 + hi2 * 4 + j;
            const int rglob = rowBase + rloc;
            const int lab   = cc ? rglob : labels[rglob];
            float vmin = 1e30f;
            #pragma unroll
            for (int n = 0; n < 4; n++) {
                float tv = acc[m][n][j] + bias[n];
                if (colg[n] == lab) {
                    if (!cc) pos[rglob] = tv;   // unique writer across grid
                    tv = 1e30f;
                }
                vmin = fminf(vmin, tv);
            }
            vmin = fminf(vmin, __shfl_xor(vmin, 1, 64));
            vmin = fminf(vmin, __shfl_xor(vmin, 2, 64));
            vmin = fminf(vmin, __shfl_xor(vmin, 4, 64));
            vmin = fminf(vmin, __shfl_xor(vmin, 8, 64));
            if (lo4 == 0) sPM[wcol * BM + rloc] = vmin;
        }
    }
    __syncthreads();
    if (t < BM) {
        const float v = fminf(sPM[t], sPM[BM + t]);
        pout[(size_t)(rowBase + t) * NCT + by] = v;
    }
}

// ---- fused: neg-min, cen-min (via cpmin), loss, global sum (atomic) ----
__global__ void loss_k(const float* __restrict__ pmin, const float* __restrict__ pos,
                       const int* __restrict__ labels, const float* __restrict__ cpmin,
                       const float* __restrict__ c2, float* __restrict__ out) {
    const int r = blockIdx.x * 256 + threadIdx.x;   // 64 blocks x 256 = 16384
    float neg = 1e30f;
    #pragma unroll
    for (int i = 0; i < 8; i++) neg = fminf(neg, pmin[(size_t)r * 8 + i]);
    const int lab = labels[r];
    float cmin = 1e30f;
    #pragma unroll
    for (int i = 0; i < 8; i++) cmin = fminf(cmin, cpmin[(size_t)lab * 8 + i]);
    const float cen = 0.5f * c2[lab] + cmin;
    float v = fmaxf(pos[r] + MARGINF - neg, 0.f) + fmaxf(MARGINF + 2.0f - cen, 0.f);
    #pragma unroll
    for (int s = 1; s < 64; s <<= 1) v += __shfl_xor(v, s, 64);
    __shared__ float sred[4];
    int lane = threadIdx.x & 63, wid = threadIdx.x >> 6;
    if (lane == 0) sred[wid] = v;
    __syncthreads();
    if (threadIdx.x == 0)
        atomicAdd(out, (sred[0] + sred[1] + sred[2] + sred[3]) * (1.0f / (float)BATCH));
}

extern "C" void kernel_launch(void* const* d_in, const int* in_sizes, int n_in,
                              void* d_out, int out_size, void* d_ws, size_t ws_size,
                              hipStream_t stream) {
    const float* x       = (const float*)d_in[0];
    const int*   labels  = (const int*)d_in[1];
    const float* centers = (const float*)d_in[2];
    float* out = (float*)d_out;

    char* ws = (char*)d_ws;
    size_t off = 0;
    unsigned short* xb = (unsigned short*)(ws + off); off += (size_t)BATCH * FDIM * 2;  // 33.55 MB
    unsigned short* cb = (unsigned short*)(ws + off); off += (size_t)CPAD * FDIM * 2;   //  2.10 MB
    float* c2    = (float*)(ws + off); off += (size_t)CPAD * 4;
    float* pmin  = (float*)(ws + off); off += (size_t)BATCH * 8 * 4;
    float* pos   = (float*)(ws + off); off += (size_t)BATCH * 4;
    float* cpmin = (float*)(ws + off); off += (size_t)CPAD * 8 * 4;

    hipMemsetAsync(out, 0, sizeof(float), stream);
    prep<<<dim3(CPAD + 2048), dim3(256), 0, stream>>>(x, centers, xb, cb, c2);
    gemm_min<<<dim3(1024 + 64), dim3(256), 0, stream>>>(xb, cb, c2, labels, pmin, cpmin, pos);
    loss_k<<<dim3(BATCH / 256), dim3(256), 0, stream>>>(pmin, pos, labels, cpmin, c2, out);
}

// Round 3
// 162.434 us; speedup vs baseline: 1.1826x; 1.1826x over previous
//
#include <hip/hip_runtime.h>
#include <hip/hip_bf16.h>
#include <stdint.h>

#define BATCH   16384
#define NCLASS  1000
#define CPAD    1024
#define FDIM    1024
#define MARGINF 5.0f

typedef __attribute__((ext_vector_type(4))) float f32x4;
typedef __attribute__((ext_vector_type(8))) short bf16x8;

__device__ __forceinline__ void gload16(const void* g, void* l) {
    __builtin_amdgcn_global_load_lds(
        (const __attribute__((address_space(1))) void*)g,
        (__attribute__((address_space(3))) void*)l, 16, 0, 0);
}

__device__ __forceinline__ unsigned short f2bf(float f) {
    __hip_bfloat16 h = __float2bfloat16(f);
    return __builtin_bit_cast(unsigned short, h);
}

__device__ __forceinline__ unsigned int pack2(float a, float b) {
    return (unsigned int)f2bf(a) | ((unsigned int)f2bf(b) << 16);
}

// ---- prep: centers fp32->bf16 + c2; pad rows zeroed, c2 pad = 1e30 ----
__global__ void prep_c(const float* __restrict__ c, unsigned short* __restrict__ cb,
                       float* __restrict__ c2) {
    const int k = blockIdx.x;     // 0..1023
    const int t = threadIdx.x;    // 256 threads, one float4 each
    if (k >= NCLASS) {
        ((ushort4*)(cb + (size_t)k * FDIM))[t] = make_ushort4(0, 0, 0, 0);
        if (t == 0) c2[k] = 1e30f;
        return;
    }
    float4 v = ((const float4*)(c + (size_t)k * FDIM))[t];
    ushort4 o;
    o.x = f2bf(v.x); o.y = f2bf(v.y); o.z = f2bf(v.z); o.w = f2bf(v.w);
    ((ushort4*)(cb + (size_t)k * FDIM))[t] = o;
    float ss = v.x * v.x + v.y * v.y + v.z * v.z + v.w * v.w;
    #pragma unroll
    for (int s = 1; s < 64; s <<= 1) ss += __shfl_xor(ss, s, 64);
    __shared__ float sred[4];
    int lane = t & 63, wid = t >> 6;
    if (lane == 0) sred[wid] = ss;
    __syncthreads();
    if (t == 0) c2[k] = sred[0] + sred[1] + sred[2] + sred[3];
}

// ---- fused GEMM + per-row partial min.  1D grid:
//   blocks [0,1024):    main  t[r,c]=0.5*c2[c]-dot(x_r, cen_c); A = x fp32, converted in-staging
//   blocks [1024,1088): CC    t[r,c]=0.5*c2[c]-dot(cen_r,cen_c); A = cb bf16 via global_load_lds
// LDS = 32768 B exactly. No min-waves bound: round-2's (256,5) caused spills
// (VGPR 88->48, WRITE_SIZE 1.15->11.5 MB, gemm 52.6->96 us).
__launch_bounds__(256)
__global__ void gemm_min(const float* __restrict__ x,             // [16384][1024] fp32
                         const unsigned short* __restrict__ cb,   // [1024][1024] bf16
                         const float* __restrict__ c2,
                         const int* __restrict__ labels,
                         float* __restrict__ pmin,                // [16384][8]
                         float* __restrict__ cpmin,               // [1024][8]
                         float* __restrict__ pos)                 // [16384]
{
    constexpr int BM = 128, BK = 64, KTOT = 1024, NCT = 8;
    __shared__ __align__(16) char sA[BM * BK * 2];   // 16 KB
    __shared__ __align__(16) char sB[BM * BK * 2];   // 16 KB

    const int bid  = blockIdx.x;
    const bool cc  = (bid >= 1024);
    const int bx   = cc ? (bid - 1024) & 7 : bid & 127;
    const int by   = cc ? (bid - 1024) >> 3 : bid >> 7;

    const int t    = threadIdx.x;
    const int lane = t & 63;
    const int wave = t >> 6;
    const int wrow = wave >> 1, wcol = wave & 1;
    const int lo4  = lane & 15, hi2 = lane >> 4;

    const int rowBase = bx * BM;
    const int colBase = by * BM;
    float* pout = cc ? cpmin : pmin;

    f32x4 acc[4][4];
    #pragma unroll
    for (int m = 0; m < 4; m++)
        #pragma unroll
        for (int n = 0; n < 4; n++) acc[m][n] = (f32x4){0.f, 0.f, 0.f, 0.f};

    const int g_t = t & 7;           // granule (8 elems / 16B bf16) within row
    const int r_t = t >> 3;          // row within 32-row chunk

    for (int kt = 0; kt < KTOT / BK; ++kt) {
        __syncthreads();
        const int k0 = kt * BK;
        // ---- B staging: centers bf16, async direct-to-LDS, pre-swizzled source ----
        #pragma unroll
        for (int cch = 0; cch < 4; ++cch) {
            const int row = cch * 32 + r_t;
            const int sc  = g_t ^ (row & 7);
            const unsigned short* gb = cb + (size_t)(colBase + row) * KTOT + k0 + sc * 8;
            char* lb = sB + (cch * 256 + (t & 192)) * 16;   // wave-uniform base; HW adds lane*16
            gload16(gb, lb);
        }
        // ---- A staging ----
        if (!cc) {
            // main: x fp32 -> reg -> bf16 -> swizzled ds_write_b128
            #pragma unroll
            for (int cch = 0; cch < 4; ++cch) {
                const int row = cch * 32 + r_t;
                const float4* gp = (const float4*)(x + (size_t)(rowBase + row) * KTOT + k0 + g_t * 8);
                float4 v0 = gp[0], v1 = gp[1];
                int4 pk;
                pk.x = pack2(v0.x, v0.y); pk.y = pack2(v0.z, v0.w);
                pk.z = pack2(v1.x, v1.y); pk.w = pack2(v1.z, v1.w);
                *(int4*)(sA + row * 128 + (g_t ^ (row & 7)) * 16) = pk;
            }
        } else {
            // CC: centers bf16 via async path
            #pragma unroll
            for (int cch = 0; cch < 4; ++cch) {
                const int row = cch * 32 + r_t;
                const int sc  = g_t ^ (row & 7);
                const unsigned short* ga = cb + (size_t)(rowBase + row) * KTOT + k0 + sc * 8;
                char* la = sA + (cch * 256 + (t & 192)) * 16;
                gload16(ga, la);
            }
        }
        __syncthreads();
        #pragma unroll
        for (int ks = 0; ks < 2; ++ks) {
            bf16x8 af[4], bfr[4];
            #pragma unroll
            for (int m = 0; m < 4; m++) {
                const int r    = wrow * 64 + m * 16 + lo4;
                const int slot = (ks * 4 + hi2) ^ (r & 7);
                af[m] = *(const bf16x8*)(sA + r * 128 + slot * 16);
            }
            #pragma unroll
            for (int n = 0; n < 4; n++) {
                const int r    = wcol * 64 + n * 16 + lo4;
                const int slot = (ks * 4 + hi2) ^ (r & 7);
                bfr[n] = *(const bf16x8*)(sB + r * 128 + slot * 16);
            }
            #pragma unroll
            for (int m = 0; m < 4; m++)
                #pragma unroll
                for (int n = 0; n < 4; n++)
                    acc[m][n] = __builtin_amdgcn_mfma_f32_16x16x32_bf16(af[m], bfr[n], acc[m][n], 0, 0, 0);
        }
    }

    // ---- epilogue: bias + exclusion + per-row min ----
    __syncthreads();                    // all LDS reads done; sA reused as sPM
    float* sPM = (float*)sA;            // [2][128]

    float bias[4]; int colg[4];
    #pragma unroll
    for (int n = 0; n < 4; n++) {
        const int col = colBase + wcol * 64 + n * 16 + lo4;
        colg[n] = col;
        bias[n] = 0.5f * c2[col];          // c2[col>=1000]=1e30 masks padding
    }
    #pragma unroll
    for (int m = 0; m < 4; m++) {
        #pragma unroll
        for (int j = 0; j < 4; j++) {
            const int rloc  = wrow * 64 + m * 16 + hi2 * 4 + j;
            const int rglob = rowBase + rloc;
            const int lab   = cc ? rglob : labels[rglob];
            float vmin = 1e30f;
            #pragma unroll
            for (int n = 0; n < 4; n++) {
                float tv = acc[m][n][j] + bias[n];
                if (colg[n] == lab) {
                    if (!cc) pos[rglob] = tv;   // unique writer across grid
                    tv = 1e30f;
                }
                vmin = fminf(vmin, tv);
            }
            vmin = fminf(vmin, __shfl_xor(vmin, 1, 64));
            vmin = fminf(vmin, __shfl_xor(vmin, 2, 64));
            vmin = fminf(vmin, __shfl_xor(vmin, 4, 64));
            vmin = fminf(vmin, __shfl_xor(vmin, 8, 64));
            if (lo4 == 0) sPM[wcol * BM + rloc] = vmin;
        }
    }
    __syncthreads();
    if (t < BM) {
        const float v = fminf(sPM[t], sPM[BM + t]);
        pout[(size_t)(rowBase + t) * NCT + by] = v;
    }
}

// ---- fused: neg-min, cen-min (via cpmin), loss, global sum (atomic) ----
__global__ void loss_k(const float* __restrict__ pmin, const float* __restrict__ pos,
                       const int* __restrict__ labels, const float* __restrict__ cpmin,
                       const float* __restrict__ c2, float* __restrict__ out) {
    const int r = blockIdx.x * 256 + threadIdx.x;   // 64 blocks x 256 = 16384
    float neg = 1e30f;
    #pragma unroll
    for (int i = 0; i < 8; i++) neg = fminf(neg, pmin[(size_t)r * 8 + i]);
    const int lab = labels[r];
    float cmin = 1e30f;
    #pragma unroll
    for (int i = 0; i < 8; i++) cmin = fminf(cmin, cpmin[(size_t)lab * 8 + i]);
    const float cen = 0.5f * c2[lab] + cmin;
    float v = fmaxf(pos[r] + MARGINF - neg, 0.f) + fmaxf(MARGINF + 2.0f - cen, 0.f);
    #pragma unroll
    for (int s = 1; s < 64; s <<= 1) v += __shfl_xor(v, s, 64);
    __shared__ float sred[4];
    int lane = threadIdx.x & 63, wid = threadIdx.x >> 6;
    if (lane == 0) sred[wid] = v;
    __syncthreads();
    if (threadIdx.x == 0)
        atomicAdd(out, (sred[0] + sred[1] + sred[2] + sred[3]) * (1.0f / (float)BATCH));
}

extern "C" void kernel_launch(void* const* d_in, const int* in_sizes, int n_in,
                              void* d_out, int out_size, void* d_ws, size_t ws_size,
                              hipStream_t stream) {
    const float* x       = (const float*)d_in[0];
    const int*   labels  = (const int*)d_in[1];
    const float* centers = (const float*)d_in[2];
    float* out = (float*)d_out;

    char* ws = (char*)d_ws;
    size_t off = 0;
    unsigned short* cb = (unsigned short*)(ws + off); off += (size_t)CPAD * FDIM * 2;   // 2.10 MB
    float* c2    = (float*)(ws + off); off += (size_t)CPAD * 4;
    float* pmin  = (float*)(ws + off); off += (size_t)BATCH * 8 * 4;
    float* pos   = (float*)(ws + off); off += (size_t)BATCH * 4;
    float* cpmin = (float*)(ws + off); off += (size_t)CPAD * 8 * 4;

    hipMemsetAsync(out, 0, sizeof(float), stream);
    prep_c<<<dim3(CPAD), dim3(256), 0, stream>>>(centers, cb, c2);
    gemm_min<<<dim3(1024 + 64), dim3(256), 0, stream>>>(x, cb, c2, labels, pmin, cpmin, pos);
    loss_k<<<dim3(BATCH / 256), dim3(256), 0, stream>>>(pmin, pos, labels, cpmin, c2, out);
}